// Round 2
// baseline (228.687 us; speedup 1.0000x reference)
//
#include <hip/hip_runtime.h>
#include <hip/hip_bf16.h>

typedef unsigned short u16;
typedef unsigned int u32;
typedef __attribute__((ext_vector_type(8))) short bf16x8;
typedef __attribute__((ext_vector_type(4))) float f32x4;

#define BATCH 2
#define NSEQ 2048
#define DIM 1024
#define HEADS 16
#define DH 64
#define MTOT (BATCH * NSEQ)   // 4096
#define QKV_N 3072
// Q scale folded with log2(e) so attention softmax runs in exp2 domain
#define QSCALE_L2E (0.125f * 1.4426950408889634f)

static __device__ __forceinline__ u16 f2bf(float f) {
    union { float f; u32 u; } v; v.f = f;
    u32 r = v.u + 0x7fffu + ((v.u >> 16) & 1u);
    return (u16)(r >> 16);
}

typedef __attribute__((address_space(1))) const void GV;
typedef __attribute__((address_space(3))) void LV;
static __device__ __forceinline__ void glds16(const void* g, void* l) {
    __builtin_amdgcn_global_load_lds((GV*)g, (LV*)l, 16, 0, 0);
}

// ---------------- LayerNorm + bf16 cast: x[4096][1024] f32 -> bf16 ----------------
__global__ __launch_bounds__(256) void ln_kernel(const float* __restrict__ x,
                                                 const float* __restrict__ gamma,
                                                 const float* __restrict__ beta,
                                                 u16* __restrict__ out) {
    int row = blockIdx.x;
    int t = threadIdx.x;
    const float4* xr = (const float4*)(x + (size_t)row * DIM);
    float4 v = xr[t];
    float s1 = v.x + v.y + v.z + v.w;
    float s2 = v.x * v.x + v.y * v.y + v.z * v.z + v.w * v.w;
    #pragma unroll
    for (int m = 1; m < 64; m <<= 1) {
        s1 += __shfl_xor(s1, m);
        s2 += __shfl_xor(s2, m);
    }
    __shared__ float r1[4], r2[4];
    int wid = t >> 6, lane = t & 63;
    if (lane == 0) { r1[wid] = s1; r2[wid] = s2; }
    __syncthreads();
    s1 = r1[0] + r1[1] + r1[2] + r1[3];
    s2 = r2[0] + r2[1] + r2[2] + r2[3];
    float mean = s1 * (1.0f / DIM);
    float var = s2 * (1.0f / DIM) - mean * mean;
    float rstd = rsqrtf(var + 1e-5f);
    const float4* gr = (const float4*)gamma;
    const float4* br = (const float4*)beta;
    float4 g = gr[t], b = br[t];
    ushort4 ov;
    ov.x = f2bf((v.x - mean) * rstd * g.x + b.x);
    ov.y = f2bf((v.y - mean) * rstd * g.y + b.y);
    ov.z = f2bf((v.z - mean) * rstd * g.z + b.z);
    ov.w = f2bf((v.w - mean) * rstd * g.w + b.w);
    *(ushort4*)(out + (size_t)row * DIM + t * 4) = ov;
}

// ---------------- transpose + cast: in[R][C] f32 -> out[C][R] bf16 ----------------
__global__ __launch_bounds__(256) void transpose_cast_kernel(const float* __restrict__ in,
                                                             u16* __restrict__ out,
                                                             int R, int C) {
    __shared__ float tile[32][33];
    int bx = blockIdx.x;  // C/32
    int by = blockIdx.y;  // R/32
    int t = threadIdx.x;
    int lc = t & 31, lr8 = t >> 5;
    #pragma unroll
    for (int i = 0; i < 4; i++) {
        int rr = lr8 + i * 8;
        tile[rr][lc] = in[(size_t)(by * 32 + rr) * C + bx * 32 + lc];
    }
    __syncthreads();
    #pragma unroll
    for (int i = 0; i < 4; i++) {
        int cc = lr8 + i * 8;
        out[(size_t)(bx * 32 + cc) * R + by * 32 + lc] = f2bf(tile[lc][cc]);
    }
}

// ---------------- GEMM: C[M][N] = A[M][K] * Bt[N][K]^T  (bf16 in, f32 acc) --------
// global_load_lds staging (width 16), linear LDS tiles [128][64] (m97 structure).
// MODE 0: scatter epilogue -> Q (scaled by 0.125*log2e), K, V in [b][h][n][d] bf16
// MODE 1: += bias, write f32
template <int MODE>
__global__ __launch_bounds__(256) void gemm_kernel(const u16* __restrict__ A,
                                                   const u16* __restrict__ Bt,
                                                   int M, int N, int K,
                                                   u16* __restrict__ q_out,
                                                   u16* __restrict__ k_out,
                                                   u16* __restrict__ v_out,
                                                   float* __restrict__ out,
                                                   const float* __restrict__ bias) {
    const int BK = 64;
    __shared__ u16 As[128 * BK];
    __shared__ u16 Bs[128 * BK];
    int bm = blockIdx.y, bn = blockIdx.x;
    int t = threadIdx.x;
    int wid = t >> 6, lane = t & 63;
    int l15 = lane & 15, l4 = lane >> 4;
    int wm = (wid >> 1) * 64, wn = (wid & 1) * 64;

    f32x4 acc[4][4] = {};

    const u16* Abase = A + (size_t)(bm * 128) * K;
    const u16* Bbase = Bt + (size_t)(bn * 128) * K;
    int lrow = lane >> 3;        // 0..7 within chunk
    int lcol = (lane & 7) * 8;   // 0..56

    for (int k0 = 0; k0 < K; k0 += BK) {
        __syncthreads();
        #pragma unroll
        for (int i = 0; i < 4; i++) {
            int c = i * 4 + wid;             // chunk 0..15, 8 rows each
            int r = c * 8 + lrow;
            glds16(Abase + (size_t)r * K + k0 + lcol, &As[c * 512]);
            glds16(Bbase + (size_t)r * K + k0 + lcol, &Bs[c * 512]);
        }
        __syncthreads();
        #pragma unroll
        for (int kk = 0; kk < BK; kk += 32) {
            bf16x8 af[4], bf[4];
            #pragma unroll
            for (int i = 0; i < 4; i++) {
                af[i] = *(const bf16x8*)(&As[(wm + i * 16 + l15) * BK + kk + l4 * 8]);
                bf[i] = *(const bf16x8*)(&Bs[(wn + i * 16 + l15) * BK + kk + l4 * 8]);
            }
            #pragma unroll
            for (int i = 0; i < 4; i++)
                #pragma unroll
                for (int j = 0; j < 4; j++)
                    acc[i][j] = __builtin_amdgcn_mfma_f32_16x16x32_bf16(af[i], bf[j], acc[i][j], 0, 0, 0);
        }
    }

    #pragma unroll
    for (int i = 0; i < 4; i++) {
        #pragma unroll
        for (int j = 0; j < 4; j++) {
            #pragma unroll
            for (int r = 0; r < 4; r++) {
                int grow = bm * 128 + wm + i * 16 + l4 * 4 + r;
                int gcol = bn * 128 + wn + j * 16 + l15;
                float val = acc[i][j][r];
                if (MODE == 0) {
                    int part = gcol >> 10;
                    int inner = gcol & 1023;
                    int h = inner >> 6, d = inner & 63;
                    int b = grow >> 11, n = grow & 2047;
                    size_t off = (((size_t)(b * HEADS + h)) * NSEQ + n) * DH + d;
                    if (part == 0) q_out[off] = f2bf(val * QSCALE_L2E);
                    else if (part == 1) k_out[off] = f2bf(val);
                    else v_out[off] = f2bf(val);
                } else {
                    out[(size_t)grow * N + gcol] = val + bias[gcol];
                }
            }
        }
    }
}

// ---------------- flash attention: QBLK=64 (4 waves x 16 rows), KVB=64 ------------
// All LDS tiles linear [*][64] with XOR swizzle  byte ^= ((row&7)<<4)  (T2-style).
// exp2 domain (Q pre-scaled by 0.125*log2e), defer-max THR=8 (T13).
__global__ __launch_bounds__(256) void attn_kernel(const u16* __restrict__ Q,
                                                   const u16* __restrict__ Kb,
                                                   const u16* __restrict__ Vb,
                                                   u16* __restrict__ out) {
    __shared__ u16 Ks[64 * 64];   // [kv][d], swizzled
    __shared__ u16 Vs[64 * 64];   // [d][kv], swizzled
    __shared__ u16 Ps[64 * 64];   // [q][kv], swizzled, per-wave 16-row slices

    // XCD-chunked swizzle: each XCD gets 4 consecutive heads (KV 2MB < 4MB L2)
    int bid = blockIdx.x;                    // 0..1023
    int wg = (bid & 7) * 128 + (bid >> 3);
    int qt = wg & 31;                        // q-tile, fast within a head
    int bh = wg >> 5;                        // 0..31

    const u16* Qh = Q + (size_t)bh * NSEQ * DH;
    const u16* Kh = Kb + (size_t)bh * NSEQ * DH;
    const u16* Vh = Vb + (size_t)bh * NSEQ * DH;

    int t = threadIdx.x, wid = t >> 6, lane = t & 63;
    int l15 = lane & 15, l4 = lane >> 4;
    int qbase = qt * 64 + wid * 16;

    // Q fragments: wave's 16 rows (A-frag row = l15), k = 0..63
    bf16x8 qf[2];
    #pragma unroll
    for (int kk = 0; kk < 2; kk++)
        qf[kk] = *(const bf16x8*)(Qh + (size_t)(qbase + l15) * DH + kk * 32 + l4 * 8);

    f32x4 o[4] = {};
    float m[4], ell[4];
    #pragma unroll
    for (int r = 0; r < 4; r++) { m[r] = -1e30f; ell[r] = 0.f; }

    int srow = t >> 2;          // 0..63
    int scol = (t & 3) * 16;    // 0,16,32,48

    for (int kt = 0; kt < NSEQ; kt += 64) {
        __syncthreads();
        // ---- stage K [kv][d] swizzled; V transposed [d][kv] swizzled ----
        {
            const u16* krow = Kh + (size_t)(kt + srow) * DH + scol;
            int4 k0 = *(const int4*)(krow);
            int4 k1 = *(const int4*)(krow + 8);
            int sw = srow & 7;
            int c0 = ((t & 3) * 2) ^ sw;
            int c1 = ((t & 3) * 2 + 1) ^ sw;
            *(int4*)(&Ks[srow * 64 + c0 * 8]) = k0;
            *(int4*)(&Ks[srow * 64 + c1 * 8]) = k1;
            const u16* vrow = Vh + (size_t)(kt + srow) * DH + scol;
            int4 v0 = *(const int4*)(vrow);
            int4 v1 = *(const int4*)(vrow + 8);
            union { int4 q; u16 s[8]; } uv0, uv1;
            uv0.q = v0; uv1.q = v1;
            #pragma unroll
            for (int i = 0; i < 8; i++) {
                int d = scol + i;
                Vs[d * 64 + ((((srow * 2) ^ ((d & 7) << 4))) >> 1)] = uv0.s[i];
            }
            #pragma unroll
            for (int i = 0; i < 8; i++) {
                int d = scol + 8 + i;
                Vs[d * 64 + ((((srow * 2) ^ ((d & 7) << 4))) >> 1)] = uv1.s[i];
            }
        }
        __syncthreads();

        // ---- S = Q K^T : s[nj][r] = S[q=l4*4+r][kv=nj*16+l15] ----
        f32x4 s[4] = {};
        #pragma unroll
        for (int kk = 0; kk < 2; kk++) {
            #pragma unroll
            for (int nj = 0; nj < 4; nj++) {
                int row = nj * 16 + l15;
                bf16x8 kf = *(const bf16x8*)(&Ks[row * 64 + (((kk * 4 + l4) ^ (row & 7)) << 3)]);
                s[nj] = __builtin_amdgcn_mfma_f32_16x16x32_bf16(qf[kk], kf, s[nj], 0, 0, 0);
            }
        }

        // ---- online softmax (exp2 domain), defer-max THR=8 ----
        float tm[4];
        #pragma unroll
        for (int r = 0; r < 4; r++) {
            float v0 = fmaxf(fmaxf(s[0][r], s[1][r]), fmaxf(s[2][r], s[3][r]));
            #pragma unroll
            for (int mk = 1; mk < 16; mk <<= 1) v0 = fmaxf(v0, __shfl_xor(v0, mk));
            tm[r] = v0;
        }
        bool need = false;
        #pragma unroll
        for (int r = 0; r < 4; r++) need |= (tm[r] > m[r] + 8.0f);
        if (__any(need)) {
            #pragma unroll
            for (int r = 0; r < 4; r++) {
                float mn = fmaxf(m[r], tm[r]);
                float sc = exp2f(m[r] - mn);
                ell[r] *= sc;
                #pragma unroll
                for (int di = 0; di < 4; di++) o[di][r] *= sc;
                m[r] = mn;
            }
        }
        #pragma unroll
        for (int r = 0; r < 4; r++) {
            float rs = 0.f;
            int row = wid * 16 + l4 * 4 + r;
            int rb = row * 64, sw = (row & 7) << 4;
            #pragma unroll
            for (int nj = 0; nj < 4; nj++) {
                float p = exp2f(s[nj][r] - m[r]);
                rs += p;
                int cb = (nj * 16 + l15) * 2;
                Ps[rb + ((cb ^ sw) >> 1)] = f2bf(p);
            }
            #pragma unroll
            for (int mk = 1; mk < 16; mk <<= 1) rs += __shfl_xor(rs, mk);
            ell[r] += rs;
        }
        asm volatile("s_waitcnt lgkmcnt(0)" ::: "memory");
        __builtin_amdgcn_sched_barrier(0);

        // ---- O += P V ----
        int prow = wid * 16 + l15;
        #pragma unroll
        for (int ks = 0; ks < 2; ks++) {
            bf16x8 pf = *(const bf16x8*)(&Ps[prow * 64 + (((ks * 4 + l4) ^ (prow & 7)) << 3)]);
            #pragma unroll
            for (int di = 0; di < 4; di++) {
                int d = di * 16 + l15;
                bf16x8 vf = *(const bf16x8*)(&Vs[d * 64 + (((ks * 4 + l4) ^ (d & 7)) << 3)]);
                o[di] = __builtin_amdgcn_mfma_f32_16x16x32_bf16(pf, vf, o[di], 0, 0, 0);
            }
        }
    }

    // epilogue: out[b*2048+n][h*64+d] bf16
    int b = bh >> 4, h = bh & 15;
    #pragma unroll
    for (int di = 0; di < 4; di++) {
        #pragma unroll
        for (int r = 0; r < 4; r++) {
            int n = qbase + l4 * 4 + r;
            int col = h * DH + di * 16 + l15;
            float val = o[di][r] * __builtin_amdgcn_rcpf(ell[r]);
            out[(size_t)(b * NSEQ + n) * DIM + col] = f2bf(val);
        }
    }
}

extern "C" void kernel_launch(void* const* d_in, const int* in_sizes, int n_in,
                              void* d_out, int out_size, void* d_ws, size_t ws_size,
                              hipStream_t stream) {
    const float* x     = (const float*)d_in[0];
    const float* gamma = (const float*)d_in[1];
    const float* beta  = (const float*)d_in[2];
    const float* w_qkv = (const float*)d_in[3];
    const float* w_out = (const float*)d_in[4];
    const float* b_out = (const float*)d_in[5];
    float* out = (float*)d_out;

    char* ws = (char*)d_ws;
    u16* x_ln  = (u16*)ws; ws += (size_t)MTOT * DIM * 2;
    u16* wqkvT = (u16*)ws; ws += (size_t)QKV_N * DIM * 2;
    u16* woutT = (u16*)ws; ws += (size_t)DIM * DIM * 2;
    u16* Qb    = (u16*)ws; ws += (size_t)BATCH * HEADS * NSEQ * DH * 2;
    u16* Kb    = (u16*)ws; ws += (size_t)BATCH * HEADS * NSEQ * DH * 2;
    u16* Vb    = (u16*)ws; ws += (size_t)BATCH * HEADS * NSEQ * DH * 2;
    u16* attn  = (u16*)ws; ws += (size_t)MTOT * DIM * 2;

    ln_kernel<<<MTOT, 256, 0, stream>>>(x, gamma, beta, x_ln);
    transpose_cast_kernel<<<dim3(QKV_N / 32, DIM / 32), 256, 0, stream>>>(w_qkv, wqkvT, DIM, QKV_N);
    transpose_cast_kernel<<<dim3(DIM / 32, DIM / 32), 256, 0, stream>>>(w_out, woutT, DIM, DIM);

    gemm_kernel<0><<<dim3(QKV_N / 128, MTOT / 128), 256, 0, stream>>>(
        x_ln, wqkvT, MTOT, QKV_N, DIM, Qb, Kb, Vb, nullptr, nullptr);

    attn_kernel<<<1024, 256, 0, stream>>>(Qb, Kb, Vb, attn);

    gemm_kernel<1><<<dim3(DIM / 128, MTOT / 128), 256, 0, stream>>>(
        attn, woutT, MTOT, DIM, DIM, nullptr, nullptr, nullptr, out, b_out);
}

// Round 3
// 178.676 us; speedup vs baseline: 1.2799x; 1.2799x over previous
//
#include <hip/hip_runtime.h>
#include <hip/hip_bf16.h>

typedef unsigned short u16;
typedef unsigned int u32;
typedef __attribute__((ext_vector_type(8))) short bf16x8;
typedef __attribute__((ext_vector_type(4))) float f32x4;
typedef __attribute__((ext_vector_type(16))) float f32x16;

#define BATCH 2
#define NSEQ 2048
#define DIM 1024
#define HEADS 16
#define DH 64
#define MTOT (BATCH * NSEQ)   // 4096
#define QKV_N 3072
// Q scale folded with log2(e) so attention softmax runs in exp2 domain
#define QSCALE_L2E (0.125f * 1.4426950408889634f)

static __device__ __forceinline__ u16 f2bf(float f) {
    union { float f; u32 u; } v; v.f = f;
    u32 r = v.u + 0x7fffu + ((v.u >> 16) & 1u);
    return (u16)(r >> 16);
}

static __device__ __forceinline__ u32 pk2(float a, float b) {
    union { __hip_bfloat162 h; u32 u; } cv;
    cv.h = __float22bfloat162_rn(float2{a, b});
    return cv.u;
}

typedef __attribute__((address_space(1))) const void GV;
typedef __attribute__((address_space(3))) void LV;
static __device__ __forceinline__ void glds16(const void* g, void* l) {
    __builtin_amdgcn_global_load_lds((GV*)g, (LV*)l, 16, 0, 0);
}

// ---------------- LayerNorm + bf16 cast: x[4096][1024] f32 -> bf16 ----------------
__global__ __launch_bounds__(256) void ln_kernel(const float* __restrict__ x,
                                                 const float* __restrict__ gamma,
                                                 const float* __restrict__ beta,
                                                 u16* __restrict__ out) {
    int row = blockIdx.x;
    int t = threadIdx.x;
    const float4* xr = (const float4*)(x + (size_t)row * DIM);
    float4 v = xr[t];
    float s1 = v.x + v.y + v.z + v.w;
    float s2 = v.x * v.x + v.y * v.y + v.z * v.z + v.w * v.w;
    #pragma unroll
    for (int m = 1; m < 64; m <<= 1) {
        s1 += __shfl_xor(s1, m);
        s2 += __shfl_xor(s2, m);
    }
    __shared__ float r1[4], r2[4];
    int wid = t >> 6, lane = t & 63;
    if (lane == 0) { r1[wid] = s1; r2[wid] = s2; }
    __syncthreads();
    s1 = r1[0] + r1[1] + r1[2] + r1[3];
    s2 = r2[0] + r2[1] + r2[2] + r2[3];
    float mean = s1 * (1.0f / DIM);
    float var = s2 * (1.0f / DIM) - mean * mean;
    float rstd = rsqrtf(var + 1e-5f);
    const float4* gr = (const float4*)gamma;
    const float4* br = (const float4*)beta;
    float4 g = gr[t], b = br[t];
    ushort4 ov;
    ov.x = f2bf((v.x - mean) * rstd * g.x + b.x);
    ov.y = f2bf((v.y - mean) * rstd * g.y + b.y);
    ov.z = f2bf((v.z - mean) * rstd * g.z + b.z);
    ov.w = f2bf((v.w - mean) * rstd * g.w + b.w);
    *(ushort4*)(out + (size_t)row * DIM + t * 4) = ov;
}

// ---------------- transpose + cast: in[R][C] f32 -> out[C][R] bf16 ----------------
__global__ __launch_bounds__(256) void transpose_cast_kernel(const float* __restrict__ in,
                                                             u16* __restrict__ out,
                                                             int R, int C) {
    __shared__ float tile[32][33];
    int bx = blockIdx.x;  // C/32
    int by = blockIdx.y;  // R/32
    int t = threadIdx.x;
    int lc = t & 31, lr8 = t >> 5;
    #pragma unroll
    for (int i = 0; i < 4; i++) {
        int rr = lr8 + i * 8;
        tile[rr][lc] = in[(size_t)(by * 32 + rr) * C + bx * 32 + lc];
    }
    __syncthreads();
    #pragma unroll
    for (int i = 0; i < 4; i++) {
        int cc = lr8 + i * 8;
        out[(size_t)(bx * 32 + cc) * R + by * 32 + lc] = f2bf(tile[lc][cc]);
    }
}

// ---------------- GEMM: C[M][N] = A[M][K] * Bt[N][K]^T  (bf16 in, f32 acc) --------
// global_load_lds staging (width 16), linear LDS tiles [128][64] (m97 structure).
// MODE 0: scatter epilogue -> Q (scaled by 0.125*log2e) [b][h][n][d],
//         K [b][h][n][d], V TRANSPOSED [b][h][d][n] (vectorized)
// MODE 1: += bias, write f32
template <int MODE>
__global__ __launch_bounds__(256) void gemm_kernel(const u16* __restrict__ A,
                                                   const u16* __restrict__ Bt,
                                                   int M, int N, int K,
                                                   u16* __restrict__ q_out,
                                                   u16* __restrict__ k_out,
                                                   u16* __restrict__ v_out,
                                                   float* __restrict__ out,
                                                   const float* __restrict__ bias) {
    const int BK = 64;
    __shared__ u16 As[128 * BK];
    __shared__ u16 Bs[128 * BK];
    int bm = blockIdx.y, bn = blockIdx.x;
    int t = threadIdx.x;
    int wid = t >> 6, lane = t & 63;
    int l15 = lane & 15, l4 = lane >> 4;
    int wm = (wid >> 1) * 64, wn = (wid & 1) * 64;

    f32x4 acc[4][4] = {};

    const u16* Abase = A + (size_t)(bm * 128) * K;
    const u16* Bbase = Bt + (size_t)(bn * 128) * K;
    int lrow = lane >> 3;        // 0..7 within chunk
    int lcol = (lane & 7) * 8;   // 0..56

    for (int k0 = 0; k0 < K; k0 += BK) {
        __syncthreads();
        #pragma unroll
        for (int i = 0; i < 4; i++) {
            int c = i * 4 + wid;             // chunk 0..15, 8 rows each
            int r = c * 8 + lrow;
            glds16(Abase + (size_t)r * K + k0 + lcol, &As[c * 512]);
            glds16(Bbase + (size_t)r * K + k0 + lcol, &Bs[c * 512]);
        }
        __syncthreads();
        #pragma unroll
        for (int kk = 0; kk < BK; kk += 32) {
            bf16x8 af[4], bf[4];
            #pragma unroll
            for (int i = 0; i < 4; i++) {
                af[i] = *(const bf16x8*)(&As[(wm + i * 16 + l15) * BK + kk + l4 * 8]);
                bf[i] = *(const bf16x8*)(&Bs[(wn + i * 16 + l15) * BK + kk + l4 * 8]);
            }
            #pragma unroll
            for (int i = 0; i < 4; i++)
                #pragma unroll
                for (int j = 0; j < 4; j++)
                    acc[i][j] = __builtin_amdgcn_mfma_f32_16x16x32_bf16(af[i], bf[j], acc[i][j], 0, 0, 0);
        }
    }

    if (MODE == 0) {
        int part = (bn * 128) >> 10;   // uniform per block (128 | 1024)
        #pragma unroll
        for (int i = 0; i < 4; i++) {
            #pragma unroll
            for (int j = 0; j < 4; j++) {
                int gcol = bn * 128 + wn + j * 16 + l15;
                int inner = gcol & 1023;
                int hh = inner >> 6, d = inner & 63;
                int n0 = bm * 128 + wm + i * 16 + l4 * 4;
                int b = n0 >> 11, n = n0 & 2047;
                if (part == 2) {
                    ushort4 w;
                    w.x = f2bf(acc[i][j][0]); w.y = f2bf(acc[i][j][1]);
                    w.z = f2bf(acc[i][j][2]); w.w = f2bf(acc[i][j][3]);
                    *(ushort4*)(v_out + (((size_t)(b * HEADS + hh)) * DH + d) * NSEQ + n) = w;
                } else {
                    size_t off = (((size_t)(b * HEADS + hh)) * NSEQ + n) * DH + d;
                    #pragma unroll
                    for (int r = 0; r < 4; r++) {
                        float val = acc[i][j][r];
                        if (part == 0) q_out[off + (size_t)r * DH] = f2bf(val * QSCALE_L2E);
                        else           k_out[off + (size_t)r * DH] = f2bf(val);
                    }
                }
            }
        }
    } else {
        #pragma unroll
        for (int i = 0; i < 4; i++) {
            #pragma unroll
            for (int j = 0; j < 4; j++) {
                #pragma unroll
                for (int r = 0; r < 4; r++) {
                    int grow = bm * 128 + wm + i * 16 + l4 * 4 + r;
                    int gcol = bn * 128 + wn + j * 16 + l15;
                    out[(size_t)grow * N + gcol] = acc[i][j][r] + bias[gcol];
                }
            }
        }
    }
}

// ---------------- flash attention, 32x32 MFMA, swapped QK^T & PV ------------------
// Per block: 4 waves x 32 q-rows (QBLK=128). KV tile 64.
// S^T = mfma(A=K, B=Q): lane holds 32 of 64 kv scores for q = lane&31
//   (kv = 32*tile + (r&3) + 8*(r>>2) + 4*(lane>>5)).
// Softmax fully in-register: fmax/add trees + one shfl_xor(32).
// P packed to bf16 in-register (16 pk2 + 8 shfl), fed as B-operand of
// O^T = mfma(A=V^T, B=P^T) -> lane holds O^T[d][q=lane&31], stats lane-aligned.
// K staged [kv][64] and V^T staged [d][64] in LDS, XOR-swizzled 16B slots.
__global__ __launch_bounds__(256) void attn_kernel(const u16* __restrict__ Q,
                                                   const u16* __restrict__ Kg,
                                                   const u16* __restrict__ VTg,
                                                   u16* __restrict__ out) {
    __shared__ u16 Ks[64 * 64];   // [kv][d]
    __shared__ u16 Vs[64 * 64];   // [d][kv]

    // XCD-chunked: each XCD owns 4 consecutive heads (all 16 q-tiles of them)
    int bid = blockIdx.x;                  // 0..511
    int wg = (bid & 7) * 64 + (bid >> 3);
    int qt = wg & 15;
    int bh = wg >> 4;                      // 0..31

    const u16* Qh  = Q   + (size_t)bh * NSEQ * DH;
    const u16* Kh  = Kg  + (size_t)bh * NSEQ * DH;
    const u16* Vh  = VTg + (size_t)bh * DH * NSEQ;  // [d][n]

    int t = threadIdx.x, wid = t >> 6, lane = t & 63;
    int q = lane & 31, h = lane >> 5;
    int qrow = qt * 128 + wid * 32 + q;

    // Q fragments (B-operand): B[k=8h+e][col=q] = Q[qrow][kk*16+8h+e]
    bf16x8 qf[4];
    #pragma unroll
    for (int kk = 0; kk < 4; kk++)
        qf[kk] = *(const bf16x8*)(Qh + (size_t)qrow * DH + kk * 16 + h * 8);

    f32x16 o0 = {}, o1 = {};
    float mrun = -1e30f, ell = 0.f;

    int srow = t >> 2;            // 0..63 (kv row for K, d row for V^T)
    int sc4 = t & 3;              // 16-u16 chunk
    int cA = (sc4 * 2) ^ (srow & 7);
    int cB = (sc4 * 2 + 1) ^ (srow & 7);
    int swq = q & 7;

    // prefetch tile 0 into regs (T14 issue-early)
    int4 ka0 = *(const int4*)(Kh + (size_t)srow * DH + sc4 * 16);
    int4 ka1 = *(const int4*)(Kh + (size_t)srow * DH + sc4 * 16 + 8);
    int4 va0 = *(const int4*)(Vh + (size_t)srow * NSEQ + sc4 * 16);
    int4 va1 = *(const int4*)(Vh + (size_t)srow * NSEQ + sc4 * 16 + 8);

    for (int kt = 0; kt < NSEQ; kt += 64) {
        __syncthreads();
        *(int4*)&Ks[srow * 64 + cA * 8] = ka0;
        *(int4*)&Ks[srow * 64 + cB * 8] = ka1;
        *(int4*)&Vs[srow * 64 + cA * 8] = va0;
        *(int4*)&Vs[srow * 64 + cB * 8] = va1;
        __syncthreads();
        if (kt + 64 < NSEQ) {   // overlap next-tile loads with compute
            ka0 = *(const int4*)(Kh + (size_t)(kt + 64 + srow) * DH + sc4 * 16);
            ka1 = *(const int4*)(Kh + (size_t)(kt + 64 + srow) * DH + sc4 * 16 + 8);
            va0 = *(const int4*)(Vh + (size_t)srow * NSEQ + kt + 64 + sc4 * 16);
            va1 = *(const int4*)(Vh + (size_t)srow * NSEQ + kt + 64 + sc4 * 16 + 8);
        }

        // ---- S^T = K * Q : s0 = kv 0..31, s1 = kv 32..63 ----
        f32x16 s0 = {}, s1 = {};
        #pragma unroll
        for (int kk = 0; kk < 4; kk++) {
            int sl = kk * 2 + h;
            bf16x8 a0 = *(const bf16x8*)(&Ks[q * 64 + ((sl ^ swq) << 3)]);
            bf16x8 a1 = *(const bf16x8*)(&Ks[(32 + q) * 64 + ((sl ^ swq) << 3)]);
            s0 = __builtin_amdgcn_mfma_f32_32x32x16_bf16(a0, qf[kk], s0, 0, 0, 0);
            s1 = __builtin_amdgcn_mfma_f32_32x32x16_bf16(a1, qf[kk], s1, 0, 0, 0);
        }

        // ---- softmax (exp2 domain), in-register ----
        float m8[8];
        #pragma unroll
        for (int i = 0; i < 8; i++)
            m8[i] = fmaxf(fmaxf(s0[i], s0[i + 8]), fmaxf(s1[i], s1[i + 8]));
        float m4a = fmaxf(m8[0], m8[4]), m4b = fmaxf(m8[1], m8[5]);
        float m4c = fmaxf(m8[2], m8[6]), m4d = fmaxf(m8[3], m8[7]);
        float tmx = fmaxf(fmaxf(m4a, m4b), fmaxf(m4c, m4d));
        tmx = fmaxf(tmx, __shfl_xor(tmx, 32));

        if (!__all(tmx <= mrun + 8.0f)) {     // defer-max (T13)
            float mnew = fmaxf(mrun, tmx);
            float scal = exp2f(mrun - mnew);
            ell *= scal;
            #pragma unroll
            for (int i = 0; i < 16; i++) { o0[i] *= scal; o1[i] *= scal; }
            mrun = mnew;
        }
        #pragma unroll
        for (int i = 0; i < 16; i++) {
            s0[i] = exp2f(s0[i] - mrun);
            s1[i] = exp2f(s1[i] - mrun);
        }
        float a8[8];
        #pragma unroll
        for (int i = 0; i < 8; i++)
            a8[i] = (s0[i] + s0[i + 8]) + (s1[i] + s1[i + 8]);
        float rs = ((a8[0] + a8[4]) + (a8[1] + a8[5])) + ((a8[2] + a8[6]) + (a8[3] + a8[7]));
        rs += __shfl_xor(rs, 32);
        ell += rs;

        // ---- pack P to bf16 words: pk[tile][group][word] (16 cvt_pk) ----
        u32 pk0[4][2], pk1[4][2];
        #pragma unroll
        for (int g = 0; g < 4; g++) {
            pk0[g][0] = pk2(s0[4 * g], s0[4 * g + 1]);
            pk0[g][1] = pk2(s0[4 * g + 2], s0[4 * g + 3]);
            pk1[g][0] = pk2(s1[4 * g], s1[4 * g + 1]);
            pk1[g][1] = pk2(s1[4 * g + 2], s1[4 * g + 3]);
        }

        // ---- O^T += V^T * P^T ----
        #pragma unroll
        for (int ks = 0; ks < 4; ks++) {
            const int g0 = 2 * (ks & 1), g1 = g0 + 1;
            u32 S0, S1, T0, T1;
            if (ks < 2) {
                S0 = h ? pk0[g1][0] : pk0[g0][0];
                S1 = h ? pk0[g1][1] : pk0[g0][1];
                T0 = h ? pk0[g0][0] : pk0[g1][0];
                T1 = h ? pk0[g0][1] : pk0[g1][1];
            } else {
                S0 = h ? pk1[g1][0] : pk1[g0][0];
                S1 = h ? pk1[g1][1] : pk1[g0][1];
                T0 = h ? pk1[g0][0] : pk1[g1][0];
                T1 = h ? pk1[g0][1] : pk1[g1][1];
            }
            u32 E0 = (u32)__shfl_xor((int)T0, 32);
            u32 E1 = (u32)__shfl_xor((int)T1, 32);
            union { u32 w[4]; bf16x8 v; } bb;
            bb.w[0] = h ? E0 : S0;
            bb.w[1] = h ? E1 : S1;
            bb.w[2] = h ? S0 : E0;
            bb.w[3] = h ? S1 : E1;
            int sl = ks * 2 + h;
            bf16x8 f0 = *(const bf16x8*)(&Vs[q * 64 + ((sl ^ swq) << 3)]);
            bf16x8 f1 = *(const bf16x8*)(&Vs[(32 + q) * 64 + ((sl ^ swq) << 3)]);
            o0 = __builtin_amdgcn_mfma_f32_32x32x16_bf16(f0, bb.v, o0, 0, 0, 0);
            o1 = __builtin_amdgcn_mfma_f32_32x32x16_bf16(f1, bb.v, o1, 0, 0, 0);
        }
    }

    // ---- epilogue: out[b*2048 + qrow][hh*64 + d], d from reg index ----
    int b = bh >> 4, hh = bh & 15;
    float rinv = __builtin_amdgcn_rcpf(ell);
    u16* orow = out + ((size_t)(b * NSEQ) + qrow) * DIM + hh * DH;
    #pragma unroll
    for (int rq = 0; rq < 4; rq++) {
        ushort4 w0, w1;
        w0.x = f2bf(o0[4 * rq] * rinv);     w0.y = f2bf(o0[4 * rq + 1] * rinv);
        w0.z = f2bf(o0[4 * rq + 2] * rinv); w0.w = f2bf(o0[4 * rq + 3] * rinv);
        w1.x = f2bf(o1[4 * rq] * rinv);     w1.y = f2bf(o1[4 * rq + 1] * rinv);
        w1.z = f2bf(o1[4 * rq + 2] * rinv); w1.w = f2bf(o1[4 * rq + 3] * rinv);
        int d0 = 8 * rq + 4 * h;
        *(ushort4*)(orow + d0) = w0;
        *(ushort4*)(orow + 32 + d0) = w1;
    }
}

extern "C" void kernel_launch(void* const* d_in, const int* in_sizes, int n_in,
                              void* d_out, int out_size, void* d_ws, size_t ws_size,
                              hipStream_t stream) {
    const float* x     = (const float*)d_in[0];
    const float* gamma = (const float*)d_in[1];
    const float* beta  = (const float*)d_in[2];
    const float* w_qkv = (const float*)d_in[3];
    const float* w_out = (const float*)d_in[4];
    const float* b_out = (const float*)d_in[5];
    float* out = (float*)d_out;

    char* ws = (char*)d_ws;
    u16* x_ln  = (u16*)ws; ws += (size_t)MTOT * DIM * 2;
    u16* wqkvT = (u16*)ws; ws += (size_t)QKV_N * DIM * 2;
    u16* woutT = (u16*)ws; ws += (size_t)DIM * DIM * 2;
    u16* Qb    = (u16*)ws; ws += (size_t)BATCH * HEADS * NSEQ * DH * 2;
    u16* Kb    = (u16*)ws; ws += (size_t)BATCH * HEADS * NSEQ * DH * 2;
    u16* VTb   = (u16*)ws; ws += (size_t)BATCH * HEADS * NSEQ * DH * 2;  // [b][h][d][n]
    u16* attn  = (u16*)ws; ws += (size_t)MTOT * DIM * 2;

    ln_kernel<<<MTOT, 256, 0, stream>>>(x, gamma, beta, x_ln);
    transpose_cast_kernel<<<dim3(QKV_N / 32, DIM / 32), 256, 0, stream>>>(w_qkv, wqkvT, DIM, QKV_N);
    transpose_cast_kernel<<<dim3(DIM / 32, DIM / 32), 256, 0, stream>>>(w_out, woutT, DIM, DIM);

    gemm_kernel<0><<<dim3(QKV_N / 128, MTOT / 128), 256, 0, stream>>>(
        x_ln, wqkvT, MTOT, QKV_N, DIM, Qb, Kb, VTb, nullptr, nullptr);

    attn_kernel<<<512, 256, 0, stream>>>(Qb, Kb, VTb, attn);

    gemm_kernel<1><<<dim3(DIM / 128, MTOT / 128), 256, 0, stream>>>(
        attn, woutT, MTOT, DIM, DIM, nullptr, nullptr, nullptr, out, b_out);
}